// Round 9
// baseline (148.859 us; speedup 1.0000x reference)
//
#include <hip/hip_runtime.h>
#include <hip/hip_bf16.h>

#define B_ 4
#define N_ 2048
#define C_ 256
#define H_ 4
#define D_ 64

typedef __attribute__((ext_vector_type(8))) short bf16x8;
typedef __attribute__((ext_vector_type(4))) float f32x4;

#define LOG2E 1.4426950408889634f

// f32 -> bf16 round-to-nearest-even (scalar)
static __device__ inline unsigned short f2bf(float f) {
    unsigned u = __builtin_bit_cast(unsigned, f);
    unsigned r = (u + 0x7fffu + ((u >> 16) & 1u)) >> 16;
    return (unsigned short)r;
}
static __device__ inline float bf2f(unsigned short h) {
    unsigned u = ((unsigned)h) << 16;
    return __builtin_bit_cast(float, u);
}
// packed pair f32 -> bf16x2 (v_cvt_pk_bf16_f32 where available)
static __device__ inline unsigned pack2(float a, float b) {
    __hip_bfloat162 h = __float22bfloat162_rn(make_float2(a, b));
    unsigned u;
    __builtin_memcpy(&u, &h, 4);
    return u;
}
static __device__ inline uint4 pk8(float4 a, float4 b) {
    uint4 u;
    u.x = pack2(a.x, a.y); u.y = pack2(a.z, a.w);
    u.z = pack2(b.x, b.y); u.w = pack2(b.z, b.w);
    return u;
}
static __device__ inline bf16x8 ld_frag(const unsigned short* p) {
    return __builtin_bit_cast(bf16x8, *(const uint4*)p);
}

// ---------------- QKV GEMM: f32 in (pack at commit), bf16 MFMA, 128x64 tile ----
// 4 waves on M. Q pre-scaled by 0.125*log2e. V written transposed+permuted:
// vt[bh][d][n_perm], perm within 64-block: p = 4*(n&15)+(n>>4).
__global__ __launch_bounds__(256) void qkv_gemm(
    const float* __restrict__ x, const float* __restrict__ w,
    const float* __restrict__ bias, unsigned short* __restrict__ qb,
    unsigned short* __restrict__ kb, unsigned short* __restrict__ vt)
{
    __shared__ __align__(16) unsigned short As[128 * 40];
    __shared__ __align__(16) unsigned short Bs[64 * 40];
    const int m0 = blockIdx.x * 128, o0 = blockIdx.y * 64;
    const int tid = threadIdx.x;
    const int wave = tid >> 6, lane = tid & 63, quad = lane >> 4, l16 = lane & 15;

    f32x4 acc[2][4];
    #pragma unroll
    for (int i = 0; i < 2; ++i)
        #pragma unroll
        for (int j = 0; j < 4; ++j) acc[i][j] = (f32x4){0.f, 0.f, 0.f, 0.f};

    const int arow = tid >> 1, acb = (tid & 1) * 16;
    const int brow = tid >> 2, bcb = (tid & 3) * 8;
    const float* asrc = &x[(size_t)(m0 + arow) * 256 + acb];
    const float* bsrc = &w[(size_t)(o0 + brow) * 256 + bcb];

    for (int k0 = 0; k0 < 256; k0 += 32) {
        __syncthreads();
        {
            float4 a0 = *(const float4*)(asrc + k0);
            float4 a1 = *(const float4*)(asrc + k0 + 4);
            float4 a2 = *(const float4*)(asrc + k0 + 8);
            float4 a3 = *(const float4*)(asrc + k0 + 12);
            float4 b0 = *(const float4*)(bsrc + k0);
            float4 b1 = *(const float4*)(bsrc + k0 + 4);
            *(uint4*)&As[arow * 40 + acb + 0] = pk8(a0, a1);
            *(uint4*)&As[arow * 40 + acb + 8] = pk8(a2, a3);
            *(uint4*)&Bs[brow * 40 + bcb] = pk8(b0, b1);
        }
        __syncthreads();
        bf16x8 a[2], b[4];
        #pragma unroll
        for (int mt = 0; mt < 2; ++mt) a[mt] = ld_frag(&As[(wave * 32 + mt * 16 + l16) * 40 + quad * 8]);
        #pragma unroll
        for (int nt = 0; nt < 4; ++nt) b[nt] = ld_frag(&Bs[(nt * 16 + l16) * 40 + quad * 8]);
        #pragma unroll
        for (int mt = 0; mt < 2; ++mt)
            #pragma unroll
            for (int nt = 0; nt < 4; ++nt)
                acc[mt][nt] = __builtin_amdgcn_mfma_f32_16x16x32_bf16(a[mt], b[nt], acc[mt][nt], 0, 0, 0);
    }

    const int three = o0 >> 8;
    const int h = (o0 >> 6) & 3;
    const int b = m0 >> 11;
    float bv[4];
    #pragma unroll
    for (int nt = 0; nt < 4; ++nt) bv[nt] = bias[o0 + nt * 16 + l16];

    if (three == 2) {
        const int n64 = ((m0 + (wave >> 1) * 64) & 2047);
        const size_t bh64 = ((size_t)b * H_ + h) * 64;
        #pragma unroll
        for (int nt = 0; nt < 4; ++nt) {
            int d = nt * 16 + l16;
            #pragma unroll
            for (int r = 0; r < 4; ++r) {
                unsigned pw = pack2(acc[0][nt][r] + bv[nt], acc[1][nt][r] + bv[nt]);
                *(unsigned*)&vt[(bh64 + d) * N_ + n64 + 16 * quad + 4 * r + 2 * (wave & 1)] = pw;
            }
        }
    } else {
        unsigned short* dst = (three == 0) ? qb : kb;
        float sc = (three == 0) ? (0.125f * LOG2E) : 1.0f;
        #pragma unroll
        for (int mt = 0; mt < 2; ++mt)
            #pragma unroll
            for (int r = 0; r < 4; ++r) {
                int m = m0 + wave * 32 + mt * 16 + quad * 4 + r;
                int n = m & 2047;
                size_t rowbase = (((size_t)b * H_ + h) * N_ + n) * D_;
                #pragma unroll
                for (int nt = 0; nt < 4; ++nt)
                    dst[rowbase + nt * 16 + l16] = f2bf((acc[mt][nt][r] + bv[nt]) * sc);
            }
    }
}

// ---------------- Flash attention: split-K x4, bias in MFMA, ext built in-kernel
#define LDK 72
#define LDKX 104   // Ks row: 64 d + 32 ext + 8 pad

__global__ __launch_bounds__(256) void attn_kernel(
    const unsigned short* __restrict__ qb, const unsigned short* __restrict__ kb,
    const unsigned short* __restrict__ vt,
    const float* __restrict__ Rm, const float* __restrict__ Pm,
    const float* __restrict__ ps_ptr,
    unsigned short* __restrict__ Opart, float* __restrict__ ml)
{
    __shared__ __align__(16) unsigned short Ks[64 * LDKX]; // [key][d | ext]
    __shared__ __align__(16) unsigned short Vs[64 * LDK];  // [d][key_perm]
    __shared__ __align__(16) unsigned short Ps[64 * LDK];  // [query][key_perm]

    const int bh = blockIdx.y;
    const int b = bh >> 2;
    const int i0 = blockIdx.x * 64;
    const int split = blockIdx.z;
    const int tid = threadIdx.x;
    const int wave = tid >> 6, lane = tid & 63;
    const int quad = lane >> 4, l16 = lane & 15;
    const float ps = ps_ptr[0];

    const size_t base = (size_t)bh * N_ * D_;
    const unsigned short* qg = qb + base;
    const unsigned short* kg = kb + base;
    const unsigned short* vg = vt + base;   // rows of length N_

    // zero the unused upper half of the ext region once (guards NaN*0)
    if (tid < 64) {
        uint4 z = {0u, 0u, 0u, 0u};
        *(uint4*)&Ks[tid * LDKX + 80] = z;
        *(uint4*)&Ks[tid * LDKX + 88] = z;
    }

    // Q A-fragments (pre-scaled by 0.125*log2e)
    const int qrow = i0 + wave * 16 + l16;
    bf16x8 aq[3];
    #pragma unroll
    for (int ks = 0; ks < 2; ++ks)
        aq[ks] = ld_frag(&qg[(size_t)qrow * D_ + ks * 32 + quad * 8]);

    // A-side bias ext: a = ps*log2e*(R_b @ P_qrow), hi/lo split
    {
        float p0 = Pm[qrow * 3 + 0], p1 = Pm[qrow * 3 + 1], p2 = Pm[qrow * 3 + 2];
        float sc = ps * LOG2E;
        unsigned short ah[3], al[3];
        #pragma unroll
        for (int c = 0; c < 3; ++c) {
            float a = (Rm[b * 9 + c * 3 + 0] * p0 + Rm[b * 9 + c * 3 + 1] * p1
                     + Rm[b * 9 + c * 3 + 2] * p2) * sc;
            ah[c] = f2bf(a);
            al[c] = f2bf(a - bf2f(ah[c]));
        }
        bf16x8 e = (bf16x8){0,0,0,0,0,0,0,0};
        if (quad == 0) {
            e[0] = (short)ah[0]; e[1] = (short)ah[1]; e[2] = (short)ah[2];
            e[3] = (short)ah[0]; e[4] = (short)ah[1]; e[5] = (short)ah[2];
            e[6] = (short)al[0]; e[7] = (short)al[1];
        } else if (quad == 1) {
            e[0] = (short)al[2];
        }
        aq[2] = e;
    }

    const bf16x8 ones = (bf16x8){0x3F80,0x3F80,0x3F80,0x3F80,0x3F80,0x3F80,0x3F80,0x3F80};

    float m_run = -1e30f;
    f32x4 o_acc[4], lacc;
    #pragma unroll
    for (int t = 0; t < 4; ++t) o_acc[t] = (f32x4){0.f, 0.f, 0.f, 0.f};
    lacc = (f32x4){0.f, 0.f, 0.f, 0.f};

    const int jbeg = split * (N_ / 4);
    const int NT = (N_ / 4) / 64;

    for (int jt = 0; jt < NT; ++jt) {
        const int j0 = jbeg + jt * 64;
        __syncthreads();   // prior iteration done reading Ks/Vs
        // stage K [key][d] + Vt [d][key_perm] (b128) and build ext from Pm
        #pragma unroll
        for (int rr = 0; rr < 2; ++rr) {
            int c = tid + rr * 256;
            int row = c >> 3, off = (c & 7) * 8;
            *(uint4*)&Ks[row * LDKX + off] = *(const uint4*)&kg[(size_t)(j0 + row) * D_ + off];
            *(uint4*)&Vs[row * LDK + off] = *(const uint4*)&vg[(size_t)row * N_ + j0 + off];
        }
        if (tid < 64) {
            const float* pp = &Pm[(size_t)(j0 + tid) * 3];
            float p0 = pp[0], p1 = pp[1], p2 = pp[2];
            unsigned u0 = f2bf(p0), u1 = f2bf(p1), u2 = f2bf(p2);
            unsigned v0 = f2bf(p0 - bf2f((unsigned short)u0));
            unsigned v1 = f2bf(p1 - bf2f((unsigned short)u1));
            unsigned v2 = f2bf(p2 - bf2f((unsigned short)u2));
            uint4 lo, hi;
            lo.x = u0 | (u1 << 16); lo.y = u2 | (v0 << 16);
            lo.z = v1 | (v2 << 16); lo.w = u0 | (u1 << 16);
            hi.x = u2; hi.y = 0u; hi.z = 0u; hi.w = 0u;
            *(uint4*)&Ks[tid * LDKX + 64] = lo;
            *(uint4*)&Ks[tid * LDKX + 72] = hi;
        }
        __syncthreads();

        // S (log2-domain logits incl. bias): 3 k-steps x 4 col-tiles
        f32x4 s[4];
        #pragma unroll
        for (int t = 0; t < 4; ++t) {
            f32x4 c = {0.f, 0.f, 0.f, 0.f};
            #pragma unroll
            for (int ks = 0; ks < 3; ++ks) {
                bf16x8 bk = ld_frag(&Ks[(l16 + 16 * t) * LDKX + ks * 32 + quad * 8]);
                c = __builtin_amdgcn_mfma_f32_16x16x32_bf16(aq[ks], bk, c, 0, 0, 0);
            }
            s[t] = c;
        }

        // strip-scalar max over the wave's 16x64 logits
        float mx = m_run;
        #pragma unroll
        for (int t = 0; t < 4; ++t)
            #pragma unroll
            for (int r = 0; r < 4; ++r)
                mx = fmaxf(mx, s[t][r]);
        #pragma unroll
        for (int off = 1; off < 64; off <<= 1)
            mx = fmaxf(mx, __shfl_xor(mx, off));
        const float alpha = exp2f(m_run - mx);
        m_run = mx;

        // p = exp2(lg - mx); pack into Ps at position 4*l16 + t (matches V perm)
        #pragma unroll
        for (int r = 0; r < 4; ++r) {
            float p0 = exp2f(s[0][r] - mx), p1 = exp2f(s[1][r] - mx);
            float p2 = exp2f(s[2][r] - mx), p3 = exp2f(s[3][r] - mx);
            uint2 w;
            w.x = pack2(p0, p1);
            w.y = pack2(p2, p3);
            *(uint2*)&Ps[(wave * 16 + quad * 4 + r) * LDK + 4 * l16] = w;
        }

        // uniform rescale of O and l (skip when max unchanged)
        if (alpha < 1.0f) {
            #pragma unroll
            for (int t = 0; t < 4; ++t)
                #pragma unroll
                for (int r = 0; r < 4; ++r)
                    o_acc[t][r] *= alpha;
            #pragma unroll
            for (int r = 0; r < 4; ++r) lacc[r] *= alpha;
        }

        // O += P V; l += P . 1 (ones-MFMA)
        #pragma unroll
        for (int ks = 0; ks < 2; ++ks) {
            bf16x8 ap = ld_frag(&Ps[(wave * 16 + l16) * LDK + ks * 32 + quad * 8]);
            #pragma unroll
            for (int t = 0; t < 4; ++t) {
                bf16x8 bv = ld_frag(&Vs[(l16 + 16 * t) * LDK + ks * 32 + quad * 8]);
                o_acc[t] = __builtin_amdgcn_mfma_f32_16x16x32_bf16(ap, bv, o_acc[t], 0, 0, 0);
            }
            lacc = __builtin_amdgcn_mfma_f32_16x16x32_bf16(ap, ones, lacc, 0, 0, 0);
        }
    }

    // store unnormalized partial O (bf16) + (m,l) per row
    const size_t pbase = (size_t)(split * 16 + bh) * N_;
    #pragma unroll
    for (int r = 0; r < 4; ++r) {
        int row = i0 + wave * 16 + quad * 4 + r;
        #pragma unroll
        for (int t = 0; t < 4; ++t)
            Opart[(pbase + row) * D_ + l16 + 16 * t] = f2bf(o_acc[t][r]);
        if (l16 == 0) {
            float2* mlp = (float2*)ml;
            mlp[pbase + row] = make_float2(m_run, lacc[r]);
        }
    }
}

// ---------------- Output projection: fused 4-way merge, hoisted weights ----------
// 64x64 tile, 4 waves on M; proj_w read f32, packed at commit.
__global__ __launch_bounds__(256) void proj_gemm(
    const unsigned short* __restrict__ Opart, const float* __restrict__ ml,
    const float* __restrict__ w, const float* __restrict__ bias,
    float* __restrict__ out)
{
    __shared__ __align__(16) unsigned short As[64 * 40];
    __shared__ __align__(16) unsigned short Bs[64 * 40];
    const int m0 = blockIdx.x * 64, o0 = blockIdx.y * 64;
    const int tid = threadIdx.x;
    const int wave = tid >> 6, lane = tid & 63, quad = lane >> 4, l16 = lane & 15;
    const float2* mlp = (const float2*)ml;

    const int srow = tid >> 2, scb = (tid & 3) * 8;
    const int sm = m0 + srow, sb = sm >> 11, sn = sm & 2047;

    // hoist 4-way merge weights per h
    float wgt[4][4];
    #pragma unroll
    for (int h = 0; h < 4; ++h) {
        size_t r1 = (size_t)(sb * 4 + h) * N_ + sn;
        float2 m0v = mlp[r1], m1v = mlp[r1 + 16 * N_];
        float2 m2v = mlp[r1 + 32 * N_], m3v = mlp[r1 + 48 * N_];
        float mm = fmaxf(fmaxf(m0v.x, m1v.x), fmaxf(m2v.x, m3v.x));
        float w0 = exp2f(m0v.x - mm), w1 = exp2f(m1v.x - mm);
        float w2 = exp2f(m2v.x - mm), w3 = exp2f(m3v.x - mm);
        float inv = 1.f / (m0v.y * w0 + m1v.y * w1 + m2v.y * w2 + m3v.y * w3);
        wgt[h][0] = w0 * inv; wgt[h][1] = w1 * inv;
        wgt[h][2] = w2 * inv; wgt[h][3] = w3 * inv;
    }

    f32x4 acc[4];
    #pragma unroll
    for (int j = 0; j < 4; ++j) acc[j] = (f32x4){0.f, 0.f, 0.f, 0.f};

    for (int k0 = 0; k0 < 256; k0 += 32) {
        const int h = k0 >> 6;
        const int d0 = (k0 & 63) + scb;
        __syncthreads();
        {   // A: 4-way merge -> bf16; B: f32 w -> bf16
            size_t r1 = (size_t)(sb * 4 + h) * N_ + sn;
            union { uint4 u; unsigned short s[8]; } a0, a1, a2, a3;
            a0.u = *(const uint4*)&Opart[r1 * D_ + d0];
            a1.u = *(const uint4*)&Opart[(r1 + 16 * N_) * D_ + d0];
            a2.u = *(const uint4*)&Opart[(r1 + 32 * N_) * D_ + d0];
            a3.u = *(const uint4*)&Opart[(r1 + 48 * N_) * D_ + d0];
            float w0 = wgt[h][0], w1 = wgt[h][1], w2 = wgt[h][2], w3 = wgt[h][3];
            uint4 mv;
            unsigned* mp = (unsigned*)&mv;
            #pragma unroll
            for (int j = 0; j < 4; ++j) {
                float lo = bf2f(a0.s[2*j]) * w0 + bf2f(a1.s[2*j]) * w1
                         + bf2f(a2.s[2*j]) * w2 + bf2f(a3.s[2*j]) * w3;
                float hi = bf2f(a0.s[2*j+1]) * w0 + bf2f(a1.s[2*j+1]) * w1
                         + bf2f(a2.s[2*j+1]) * w2 + bf2f(a3.s[2*j+1]) * w3;
                mp[j] = pack2(lo, hi);
            }
            *(uint4*)&As[srow * 40 + scb] = mv;
            float4 b0 = *(const float4*)&w[(size_t)(o0 + srow) * 256 + k0 + scb];
            float4 b1 = *(const float4*)&w[(size_t)(o0 + srow) * 256 + k0 + scb + 4];
            *(uint4*)&Bs[srow * 40 + scb] = pk8(b0, b1);
        }
        __syncthreads();
        bf16x8 a = ld_frag(&As[(wave * 16 + l16) * 40 + quad * 8]);
        #pragma unroll
        for (int nt = 0; nt < 4; ++nt) {
            bf16x8 b = ld_frag(&Bs[(nt * 16 + l16) * 40 + quad * 8]);
            acc[nt] = __builtin_amdgcn_mfma_f32_16x16x32_bf16(a, b, acc[nt], 0, 0, 0);
        }
    }

    float bv[4];
    #pragma unroll
    for (int nt = 0; nt < 4; ++nt) bv[nt] = bias[o0 + nt * 16 + l16];
    #pragma unroll
    for (int r = 0; r < 4; ++r) {
        int m = m0 + wave * 16 + quad * 4 + r;
        #pragma unroll
        for (int nt = 0; nt < 4; ++nt)
            out[(size_t)m * 256 + o0 + nt * 16 + l16] = acc[nt][r] + bv[nt];
    }
}

extern "C" void kernel_launch(void* const* d_in, const int* in_sizes, int n_in,
                              void* d_out, int out_size, void* d_ws, size_t ws_size,
                              hipStream_t stream) {
    const float* x       = (const float*)d_in[0];
    const float* Rm      = (const float*)d_in[1];
    const float* Pm      = (const float*)d_in[2];
    const float* qkv_w   = (const float*)d_in[3];
    const float* qkv_b   = (const float*)d_in[4];
    const float* proj_w  = (const float*)d_in[5];
    const float* proj_b  = (const float*)d_in[6];
    const float* pos_scl = (const float*)d_in[7];
    float* out = (float*)d_out;

    const size_t NE = (size_t)B_ * H_ * N_ * D_;   // 2,097,152
    unsigned short* qb    = (unsigned short*)d_ws; // 4 MB each
    unsigned short* kb    = qb  + NE;
    unsigned short* vtb   = kb  + NE;
    unsigned short* opart = vtb + NE;              // 4*NE = 16 MB
    float*          mlb   = (float*)(opart + 4 * NE);  // 4*16*2048 float2 = 1 MB

    qkv_gemm<<<dim3(64, 12), 256, 0, stream>>>(x, qkv_w, qkv_b, qb, kb, vtb);
    attn_kernel<<<dim3(32, 16, 4), 256, 0, stream>>>(qb, kb, vtb, Rm, Pm, pos_scl, opart, mlb);
    proj_gemm<<<dim3(128, 4), 256, 0, stream>>>(opart, mlb, proj_w, proj_b, out);
}

// Round 10
// 140.097 us; speedup vs baseline: 1.0625x; 1.0625x over previous
//
#include <hip/hip_runtime.h>
#include <hip/hip_bf16.h>

#define B_ 4
#define N_ 2048
#define C_ 256
#define H_ 4
#define D_ 64

typedef __attribute__((ext_vector_type(8))) short bf16x8;
typedef __attribute__((ext_vector_type(4))) float f32x4;

#define LOG2E 1.4426950408889634f

// f32 -> bf16 round-to-nearest-even (scalar)
static __device__ inline unsigned short f2bf(float f) {
    unsigned u = __builtin_bit_cast(unsigned, f);
    unsigned r = (u + 0x7fffu + ((u >> 16) & 1u)) >> 16;
    return (unsigned short)r;
}
static __device__ inline float bf2f(unsigned short h) {
    unsigned u = ((unsigned)h) << 16;
    return __builtin_bit_cast(float, u);
}
// packed pair f32 -> bf16x2 (v_cvt_pk_bf16_f32 where available)
static __device__ inline unsigned pack2(float a, float b) {
    __hip_bfloat162 h = __float22bfloat162_rn(make_float2(a, b));
    unsigned u;
    __builtin_memcpy(&u, &h, 4);
    return u;
}
static __device__ inline bf16x8 ld_frag(const unsigned short* p) {
    return __builtin_bit_cast(bf16x8, *(const uint4*)p);
}

// ---------------- cvt prepass: x / qkv_w / proj_w -> bf16 ----------------
__global__ __launch_bounds__(256) void cvt_kernel(
    const float* __restrict__ x, const float* __restrict__ qkv_w,
    const float* __restrict__ proj_w,
    unsigned short* __restrict__ xb, unsigned short* __restrict__ wqb,
    unsigned short* __restrict__ wpb)
{
    const int bid = blockIdx.x, tid = threadIdx.x;
    const float* s; unsigned short* d; int i;
    if (bid < 1024)      { s = x;      d = xb;  i = (bid * 256 + tid) * 8; }
    else if (bid < 1120) { s = qkv_w;  d = wqb; i = ((bid - 1024) * 256 + tid) * 8; }
    else                 { s = proj_w; d = wpb; i = ((bid - 1120) * 256 + tid) * 8; }
    float4 a = *(const float4*)(s + i);
    float4 b = *(const float4*)(s + i + 4);
    uint4 u;
    u.x = pack2(a.x, a.y); u.y = pack2(a.z, a.w);
    u.z = pack2(b.x, b.y); u.w = pack2(b.z, b.w);
    *(uint4*)(d + i) = u;
}

// ---------------- QKV GEMM: bf16, 128x128 tile, 4 waves 2x2, BK=32 ----------
// Q pre-scaled by 0.125*log2e. V written transposed+permuted:
// vt[bh][d][n_perm], perm within 64-block: p = 4*(n&15)+((n>>4)&3).
__global__ __launch_bounds__(256) void qkv_gemm(
    const unsigned short* __restrict__ xb, const unsigned short* __restrict__ wb,
    const float* __restrict__ bias, unsigned short* __restrict__ qb,
    unsigned short* __restrict__ kb, unsigned short* __restrict__ vt)
{
    __shared__ __align__(16) unsigned short As[128 * 40];
    __shared__ __align__(16) unsigned short Bs[128 * 40];
    const int m0 = blockIdx.x * 128, o0 = blockIdx.y * 128;
    const int tid = threadIdx.x;
    const int wave = tid >> 6, lane = tid & 63, quad = lane >> 4, l16 = lane & 15;
    const int wy = wave >> 1, wx = wave & 1;

    f32x4 acc[4][4];
    #pragma unroll
    for (int i = 0; i < 4; ++i)
        #pragma unroll
        for (int j = 0; j < 4; ++j) acc[i][j] = (f32x4){0.f, 0.f, 0.f, 0.f};

    const int srow = tid >> 1, soff = (tid & 1) * 16;   // 128 rows x 32 cols staging

    for (int k0 = 0; k0 < 256; k0 += 32) {
        __syncthreads();
        {
            const unsigned short* sa = &xb[(size_t)(m0 + srow) * 256 + k0 + soff];
            const unsigned short* sb = &wb[(size_t)(o0 + srow) * 256 + k0 + soff];
            *(uint4*)&As[srow * 40 + soff + 0] = *(const uint4*)(sa + 0);
            *(uint4*)&As[srow * 40 + soff + 8] = *(const uint4*)(sa + 8);
            *(uint4*)&Bs[srow * 40 + soff + 0] = *(const uint4*)(sb + 0);
            *(uint4*)&Bs[srow * 40 + soff + 8] = *(const uint4*)(sb + 8);
        }
        __syncthreads();
        bf16x8 a[4], b[4];
        #pragma unroll
        for (int mt = 0; mt < 4; ++mt) a[mt] = ld_frag(&As[(wy * 64 + mt * 16 + l16) * 40 + quad * 8]);
        #pragma unroll
        for (int nt = 0; nt < 4; ++nt) b[nt] = ld_frag(&Bs[(wx * 64 + nt * 16 + l16) * 40 + quad * 8]);
        #pragma unroll
        for (int mt = 0; mt < 4; ++mt)
            #pragma unroll
            for (int nt = 0; nt < 4; ++nt)
                acc[mt][nt] = __builtin_amdgcn_mfma_f32_16x16x32_bf16(a[mt], b[nt], acc[mt][nt], 0, 0, 0);
    }

    const int sec = o0 + wx * 64;            // this wave's 64 output cols
    const int three = sec >> 8;
    const int h = (sec >> 6) & 3;
    const int b = m0 >> 11;
    float bv[4];
    #pragma unroll
    for (int nt = 0; nt < 4; ++nt) bv[nt] = bias[sec + nt * 16 + l16];

    if (three == 2) {
        // V: n = m0 + wy*64 + mt*16 + quad*4 + r; p = 16*quad + 4*r + mt (mt fast)
        const int n64 = (m0 + wy * 64) & 2047;
        const size_t bh64 = ((size_t)b * H_ + h) * 64;
        #pragma unroll
        for (int nt = 0; nt < 4; ++nt) {
            int d = nt * 16 + l16;
            #pragma unroll
            for (int r = 0; r < 4; ++r) {
                ushort4 v;
                v.x = f2bf(acc[0][nt][r] + bv[nt]);
                v.y = f2bf(acc[1][nt][r] + bv[nt]);
                v.z = f2bf(acc[2][nt][r] + bv[nt]);
                v.w = f2bf(acc[3][nt][r] + bv[nt]);
                *(ushort4*)&vt[(bh64 + d) * N_ + n64 + 16 * quad + 4 * r] = v;
            }
        }
    } else {
        unsigned short* dst = (three == 0) ? qb : kb;
        float sc = (three == 0) ? (0.125f * LOG2E) : 1.0f;
        #pragma unroll
        for (int mt = 0; mt < 4; ++mt)
            #pragma unroll
            for (int r = 0; r < 4; ++r) {
                int n = (m0 + wy * 64 + mt * 16 + quad * 4 + r) & 2047;
                size_t rowbase = (((size_t)b * H_ + h) * N_ + n) * D_;
                #pragma unroll
                for (int nt = 0; nt < 4; ++nt)
                    dst[rowbase + nt * 16 + l16] = f2bf((acc[mt][nt][r] + bv[nt]) * sc);
            }
    }
}

// ---------------- Flash attention: split-K x2, bias in MFMA, ext built in-kernel
#define LDK 72
#define LDKX 104   // Ks row: 64 d + 32 ext + 8 pad

__global__ __launch_bounds__(256) void attn_kernel(
    const unsigned short* __restrict__ qb, const unsigned short* __restrict__ kb,
    const unsigned short* __restrict__ vt,
    const float* __restrict__ Rm, const float* __restrict__ Pm,
    const float* __restrict__ ps_ptr,
    unsigned short* __restrict__ Opart, float* __restrict__ ml)
{
    __shared__ __align__(16) unsigned short Ks[64 * LDKX]; // [key][d | ext]
    __shared__ __align__(16) unsigned short Vs[64 * LDK];  // [d][key_perm]
    __shared__ __align__(16) unsigned short Ps[64 * LDK];  // [query][key_perm]

    const int bh = blockIdx.y;
    const int b = bh >> 2;
    const int i0 = blockIdx.x * 64;
    const int split = blockIdx.z;
    const int tid = threadIdx.x;
    const int wave = tid >> 6, lane = tid & 63;
    const int quad = lane >> 4, l16 = lane & 15;
    const float ps = ps_ptr[0];

    const size_t base = (size_t)bh * N_ * D_;
    const unsigned short* qg = qb + base;
    const unsigned short* kg = kb + base;
    const unsigned short* vg = vt + base;   // rows of length N_

    // zero the unused upper half of the ext region once (guards NaN*0)
    if (tid < 64) {
        uint4 z = {0u, 0u, 0u, 0u};
        *(uint4*)&Ks[tid * LDKX + 80] = z;
        *(uint4*)&Ks[tid * LDKX + 88] = z;
    }

    // Q A-fragments (pre-scaled by 0.125*log2e)
    const int qrow = i0 + wave * 16 + l16;
    bf16x8 aq[3];
    #pragma unroll
    for (int ks = 0; ks < 2; ++ks)
        aq[ks] = ld_frag(&qg[(size_t)qrow * D_ + ks * 32 + quad * 8]);

    // A-side bias ext: a = ps*log2e*(R_b @ P_qrow), hi/lo split
    {
        float p0 = Pm[qrow * 3 + 0], p1 = Pm[qrow * 3 + 1], p2 = Pm[qrow * 3 + 2];
        float sc = ps * LOG2E;
        unsigned short ah[3], al[3];
        #pragma unroll
        for (int c = 0; c < 3; ++c) {
            float a = (Rm[b * 9 + c * 3 + 0] * p0 + Rm[b * 9 + c * 3 + 1] * p1
                     + Rm[b * 9 + c * 3 + 2] * p2) * sc;
            ah[c] = f2bf(a);
            al[c] = f2bf(a - bf2f(ah[c]));
        }
        bf16x8 e = (bf16x8){0,0,0,0,0,0,0,0};
        if (quad == 0) {
            e[0] = (short)ah[0]; e[1] = (short)ah[1]; e[2] = (short)ah[2];
            e[3] = (short)ah[0]; e[4] = (short)ah[1]; e[5] = (short)ah[2];
            e[6] = (short)al[0]; e[7] = (short)al[1];
        } else if (quad == 1) {
            e[0] = (short)al[2];
        }
        aq[2] = e;
    }

    const bf16x8 ones = (bf16x8){0x3F80,0x3F80,0x3F80,0x3F80,0x3F80,0x3F80,0x3F80,0x3F80};

    float m_run = -1e30f;
    f32x4 o_acc[4], lacc;
    #pragma unroll
    for (int t = 0; t < 4; ++t) o_acc[t] = (f32x4){0.f, 0.f, 0.f, 0.f};
    lacc = (f32x4){0.f, 0.f, 0.f, 0.f};

    const int jbeg = split * (N_ / 2);
    const int NT = (N_ / 2) / 64;

    for (int jt = 0; jt < NT; ++jt) {
        const int j0 = jbeg + jt * 64;
        __syncthreads();   // prior iteration done reading Ks/Vs
        // stage K [key][d] + Vt [d][key_perm] (b128) and build ext from Pm
        #pragma unroll
        for (int rr = 0; rr < 2; ++rr) {
            int c = tid + rr * 256;
            int row = c >> 3, off = (c & 7) * 8;
            *(uint4*)&Ks[row * LDKX + off] = *(const uint4*)&kg[(size_t)(j0 + row) * D_ + off];
            *(uint4*)&Vs[row * LDK + off] = *(const uint4*)&vg[(size_t)row * N_ + j0 + off];
        }
        if (tid < 64) {
            const float* pp = &Pm[(size_t)(j0 + tid) * 3];
            float p0 = pp[0], p1 = pp[1], p2 = pp[2];
            unsigned u0 = f2bf(p0), u1 = f2bf(p1), u2 = f2bf(p2);
            unsigned v0 = f2bf(p0 - bf2f((unsigned short)u0));
            unsigned v1 = f2bf(p1 - bf2f((unsigned short)u1));
            unsigned v2 = f2bf(p2 - bf2f((unsigned short)u2));
            uint4 lo, hi;
            lo.x = u0 | (u1 << 16); lo.y = u2 | (v0 << 16);
            lo.z = v1 | (v2 << 16); lo.w = u0 | (u1 << 16);
            hi.x = u2; hi.y = 0u; hi.z = 0u; hi.w = 0u;
            *(uint4*)&Ks[tid * LDKX + 64] = lo;
            *(uint4*)&Ks[tid * LDKX + 72] = hi;
        }
        __syncthreads();

        // S (log2-domain logits incl. bias): 3 k-steps x 4 col-tiles
        f32x4 s[4];
        #pragma unroll
        for (int t = 0; t < 4; ++t) {
            f32x4 c = {0.f, 0.f, 0.f, 0.f};
            #pragma unroll
            for (int ks = 0; ks < 3; ++ks) {
                bf16x8 bk = ld_frag(&Ks[(l16 + 16 * t) * LDKX + ks * 32 + quad * 8]);
                c = __builtin_amdgcn_mfma_f32_16x16x32_bf16(aq[ks], bk, c, 0, 0, 0);
            }
            s[t] = c;
        }

        // strip-scalar max over the wave's 16x64 logits
        float mx = m_run;
        #pragma unroll
        for (int t = 0; t < 4; ++t)
            #pragma unroll
            for (int r = 0; r < 4; ++r)
                mx = fmaxf(mx, s[t][r]);
        #pragma unroll
        for (int off = 1; off < 64; off <<= 1)
            mx = fmaxf(mx, __shfl_xor(mx, off));
        const float alpha = exp2f(m_run - mx);
        m_run = mx;

        // p = exp2(lg - mx); pack into Ps at position 4*l16 + t (matches V perm)
        #pragma unroll
        for (int r = 0; r < 4; ++r) {
            float p0 = exp2f(s[0][r] - mx), p1 = exp2f(s[1][r] - mx);
            float p2 = exp2f(s[2][r] - mx), p3 = exp2f(s[3][r] - mx);
            uint2 w;
            w.x = pack2(p0, p1);
            w.y = pack2(p2, p3);
            *(uint2*)&Ps[(wave * 16 + quad * 4 + r) * LDK + 4 * l16] = w;
        }

        // uniform rescale of O and l (skip when max unchanged)
        if (alpha < 1.0f) {
            #pragma unroll
            for (int t = 0; t < 4; ++t)
                #pragma unroll
                for (int r = 0; r < 4; ++r)
                    o_acc[t][r] *= alpha;
            #pragma unroll
            for (int r = 0; r < 4; ++r) lacc[r] *= alpha;
        }

        // O += P V; l += P . 1 (ones-MFMA)
        #pragma unroll
        for (int ks = 0; ks < 2; ++ks) {
            bf16x8 ap = ld_frag(&Ps[(wave * 16 + l16) * LDK + ks * 32 + quad * 8]);
            #pragma unroll
            for (int t = 0; t < 4; ++t) {
                bf16x8 bv = ld_frag(&Vs[(l16 + 16 * t) * LDK + ks * 32 + quad * 8]);
                o_acc[t] = __builtin_amdgcn_mfma_f32_16x16x32_bf16(ap, bv, o_acc[t], 0, 0, 0);
            }
            lacc = __builtin_amdgcn_mfma_f32_16x16x32_bf16(ap, ones, lacc, 0, 0, 0);
        }
    }

    // store unnormalized partial O (bf16) + (m,l) per row
    const size_t pbase = (size_t)(split * 16 + bh) * N_;
    #pragma unroll
    for (int r = 0; r < 4; ++r) {
        int row = i0 + wave * 16 + quad * 4 + r;
        #pragma unroll
        for (int t = 0; t < 4; ++t)
            Opart[(pbase + row) * D_ + l16 + 16 * t] = f2bf(o_acc[t][r]);
        if (l16 == 0) {
            float2* mlp = (float2*)ml;
            mlp[pbase + row] = make_float2(m_run, lacc[r]);
        }
    }
}

// ---------------- Output projection: fused 2-way merge, hoisted weights ----------
// 64x64 tile, 4 waves on M; bf16 weights from cvt prepass.
__global__ __launch_bounds__(256) void proj_gemm(
    const unsigned short* __restrict__ Opart, const float* __restrict__ ml,
    const unsigned short* __restrict__ wb, const float* __restrict__ bias,
    float* __restrict__ out)
{
    __shared__ __align__(16) unsigned short As[64 * 40];
    __shared__ __align__(16) unsigned short Bs[64 * 40];
    const int m0 = blockIdx.x * 64, o0 = blockIdx.y * 64;
    const int tid = threadIdx.x;
    const int wave = tid >> 6, lane = tid & 63, quad = lane >> 4, l16 = lane & 15;
    const float2* mlp = (const float2*)ml;

    const int srow = tid >> 2, scb = (tid & 3) * 8;
    const int sm = m0 + srow, sb = sm >> 11, sn = sm & 2047;

    // hoist 2-way merge weights per h
    float w1h[4], w2h[4];
    #pragma unroll
    for (int h = 0; h < 4; ++h) {
        size_t r1 = (size_t)(sb * 4 + h) * N_ + sn;
        float2 ml1 = mlp[r1], ml2 = mlp[r1 + 16 * N_];
        float mm = fmaxf(ml1.x, ml2.x);
        float w1 = exp2f(ml1.x - mm), w2 = exp2f(ml2.x - mm);
        float inv = 1.f / (ml1.y * w1 + ml2.y * w2);
        w1h[h] = w1 * inv; w2h[h] = w2 * inv;
    }

    f32x4 acc[4];
    #pragma unroll
    for (int j = 0; j < 4; ++j) acc[j] = (f32x4){0.f, 0.f, 0.f, 0.f};

    for (int k0 = 0; k0 < 256; k0 += 32) {
        const int h = k0 >> 6;
        const int d0 = (k0 & 63) + scb;
        __syncthreads();
        {   // A: 2-way merge -> bf16; B: bf16 copy
            size_t r1 = (size_t)(sb * 4 + h) * N_ + sn;
            union { uint4 u; unsigned short s[8]; } a1, a2;
            a1.u = *(const uint4*)&Opart[r1 * D_ + d0];
            a2.u = *(const uint4*)&Opart[(r1 + 16 * N_) * D_ + d0];
            float w1 = w1h[h], w2 = w2h[h];
            uint4 mv;
            unsigned* mp = (unsigned*)&mv;
            #pragma unroll
            for (int j = 0; j < 4; ++j)
                mp[j] = pack2(bf2f(a1.s[2*j]) * w1 + bf2f(a2.s[2*j]) * w2,
                              bf2f(a1.s[2*j+1]) * w1 + bf2f(a2.s[2*j+1]) * w2);
            *(uint4*)&As[srow * 40 + scb] = mv;
            *(uint4*)&Bs[srow * 40 + scb] = *(const uint4*)&wb[(size_t)(o0 + srow) * 256 + k0 + scb];
        }
        __syncthreads();
        bf16x8 a = ld_frag(&As[(wave * 16 + l16) * 40 + quad * 8]);
        #pragma unroll
        for (int nt = 0; nt < 4; ++nt) {
            bf16x8 b = ld_frag(&Bs[(nt * 16 + l16) * 40 + quad * 8]);
            acc[nt] = __builtin_amdgcn_mfma_f32_16x16x32_bf16(a, b, acc[nt], 0, 0, 0);
        }
    }

    float bv[4];
    #pragma unroll
    for (int nt = 0; nt < 4; ++nt) bv[nt] = bias[o0 + nt * 16 + l16];
    #pragma unroll
    for (int r = 0; r < 4; ++r) {
        int m = m0 + wave * 16 + quad * 4 + r;
        #pragma unroll
        for (int nt = 0; nt < 4; ++nt)
            out[(size_t)m * 256 + o0 + nt * 16 + l16] = acc[nt][r] + bv[nt];
    }
}

extern "C" void kernel_launch(void* const* d_in, const int* in_sizes, int n_in,
                              void* d_out, int out_size, void* d_ws, size_t ws_size,
                              hipStream_t stream) {
    const float* x       = (const float*)d_in[0];
    const float* Rm      = (const float*)d_in[1];
    const float* Pm      = (const float*)d_in[2];
    const float* qkv_w   = (const float*)d_in[3];
    const float* qkv_b   = (const float*)d_in[4];
    const float* proj_w  = (const float*)d_in[5];
    const float* proj_b  = (const float*)d_in[6];
    const float* pos_scl = (const float*)d_in[7];
    float* out = (float*)d_out;

    const size_t NE = (size_t)B_ * H_ * N_ * D_;   // 2,097,152
    unsigned short* xb    = (unsigned short*)d_ws; // 4 MB
    unsigned short* wqb   = xb   + NE;             // 768*256
    unsigned short* wpb   = wqb  + 768 * 256;      // 256*256
    unsigned short* qb    = wpb  + 256 * 256;      // 4 MB each
    unsigned short* kb    = qb   + NE;
    unsigned short* vtb   = kb   + NE;
    unsigned short* opart = vtb  + NE;             // 2*NE = 8 MB
    float*          mlb   = (float*)(opart + 2 * NE);  // 2*16*2048 float2 = 512 KB

    cvt_kernel<<<1152, 256, 0, stream>>>(x, qkv_w, proj_w, xb, wqb, wpb);
    qkv_gemm<<<dim3(64, 6), 256, 0, stream>>>(xb, wqb, qkv_b, qb, kb, vtb);
    attn_kernel<<<dim3(32, 16, 2), 256, 0, stream>>>(qb, kb, vtb, Rm, Pm, pos_scl, opart, mlb);
    proj_gemm<<<dim3(128, 4), 256, 0, stream>>>(opart, mlb, wpb, proj_b, out);
}